// Round 2
// baseline (762.855 us; speedup 1.0000x reference)
//
#include <hip/hip_runtime.h>
#include <math.h>

typedef __attribute__((ext_vector_type(8))) short short8;
typedef __attribute__((ext_vector_type(4))) float f32x4;

// fp32 -> bf16 bits, round-to-nearest-even
static __device__ __forceinline__ unsigned short f2bf(float f) {
  unsigned int u = __float_as_uint(f);
  u = u + 0x7fffu + ((u >> 16) & 1u);
  return (unsigned short)(u >> 16);
}

// ---------------- kernel 1: supT[batch][col][n] (bf16) = (x @ W)^T ----------------
// tile 64 rows x 128 cols, fp32 VALU (tiny: 0.5 GFLOP)
__global__ __launch_bounds__(256) void support_kernel(
    const float* __restrict__ x, const float* __restrict__ w,
    unsigned short* __restrict__ supT, int N) {
  __shared__ float aT[64][65];    // transposed x tile (+1 pad)
  __shared__ float bs[64][132];   // W tile (+4 pad)

  const int tid = threadIdx.x;
  const long long r0 = (long long)blockIdx.x * 64;
  const float* Ab = x + r0 * 128;
  const int tx = tid & 15;        // col group: cols tx*8..+7
  const int ty = tid >> 4;        // row group: rows ty*4..+3

  float acc[4][8] = {};
  const int ar = tid & 63, ak = (tid >> 6) * 16;
  const int bk = tid >> 2, bc = (tid & 3) * 32;

  for (int k0 = 0; k0 < 128; k0 += 64) {
    const float4* asrc = (const float4*)(Ab + (long long)ar * 128 + k0 + ak);
    #pragma unroll
    for (int j = 0; j < 4; ++j) {
      float4 v = asrc[j];
      aT[ak + 4*j + 0][ar] = v.x;
      aT[ak + 4*j + 1][ar] = v.y;
      aT[ak + 4*j + 2][ar] = v.z;
      aT[ak + 4*j + 3][ar] = v.w;
    }
    const float4* bsrc = (const float4*)(w + (long long)(k0 + bk) * 128 + bc);
    #pragma unroll
    for (int j = 0; j < 8; ++j) *(float4*)&bs[bk][bc + 4*j] = bsrc[j];
    __syncthreads();
    #pragma unroll 16
    for (int k = 0; k < 64; ++k) {
      float a[4], b[8];
      *(float4*)a      = *(const float4*)&aT[k][ty*4];
      *(float4*)&b[0]  = *(const float4*)&bs[k][tx*8];
      *(float4*)&b[4]  = *(const float4*)&bs[k][tx*8 + 4];
      #pragma unroll
      for (int i = 0; i < 4; ++i)
        #pragma unroll
        for (int j = 0; j < 8; ++j)
          acc[i][j] = fmaf(a[i], b[j], acc[i][j]);
    }
    __syncthreads();
  }
  // write transposed bf16: supT[batch*128*N + col*N + n]
  const int batch = (int)(r0 / N);
  const int nloc = (int)(r0 % N) + ty * 4;
  #pragma unroll
  for (int j = 0; j < 8; ++j) {
    const int col = tx * 8 + j;
    ushort4 pv;
    pv.x = f2bf(acc[0][j]); pv.y = f2bf(acc[1][j]);
    pv.z = f2bf(acc[2][j]); pv.w = f2bf(acc[3][j]);
    *(ushort4*)&supT[(size_t)batch * 128 * N + (size_t)col * N + nloc] = pv;
  }
}

// ---------------- kernel 2: out = LIF(adj @ support + bias) ----------------
// tile 32 rows x 128 cols, K-tile 128.
// Software-pipelined: supT fragments prefetched 1 K-tile ahead (reg dbuf),
// adj fp32 prefetched 2 K-tiles ahead (reg dbuf), raw s_barrier (no vmcnt(0)
// drain) so ~12 global loads stay in flight across every barrier.
#define BK2 128
#define ASTR 136   // shorts; 272 B row stride -> 4-bank shift/row, 16B-aligned

__global__ __launch_bounds__(256) void spike_gemm_kernel(
    const float* __restrict__ adj, const unsigned short* __restrict__ supT,
    const float* __restrict__ bias, const int* __restrict__ tsp,
    float* __restrict__ out, int N) {
  __shared__ __align__(16) unsigned short As[32][ASTR];  // 8704 B, single buffer

  const int tid = threadIdx.x;
  const int lane = tid & 63;
  const int wave = tid >> 6;           // wave w -> cols w*32..w*32+31
  const int batch = blockIdx.y;
  const int n0 = blockIdx.x * 32;

  const float* Ab = adj + ((size_t)batch * N + n0) * N;
  const unsigned short* Bb = supT + (size_t)batch * 128 * N;

  // A staging: thread -> rows (tid>>4), (tid>>4)+16; k-chunk (tid&15)*8
  const int ar = tid >> 4;
  const int akq = tid & 15;

  // MFMA fragment coords (16x16x32): m/n = lane&15, k-group = lane>>4
  const int fm = lane & 15;
  const int kg = lane >> 4;

  f32x4 acc[2][2] = {};   // [row-tile][col-tile]

  const int NT = N / BK2;  // 64

  // global base pointers (k advances via k0 offset)
  const unsigned short* bp0 = Bb + (size_t)(wave * 32 + 0 * 16 + fm) * N + kg * 8;
  const unsigned short* bp1 = Bb + (size_t)(wave * 32 + 1 * 16 + fm) * N + kg * 8;
  const float* ap0 = Ab + (size_t)ar * N + akq * 8;
  const float* ap1 = Ab + (size_t)(ar + 16) * N + akq * 8;

  uint4 bfrA[2][4], bfrB[2][4];   // supT frag double-buffer (reg)
  float4 adjA[4], adjB[4];        // adj fp32 double-buffer (reg)

  auto issueB = [&](uint4 (&dst)[2][4], int k0) {
    #pragma unroll
    for (int ks = 0; ks < 4; ++ks) {
      dst[0][ks] = *(const uint4*)(bp0 + k0 + ks * 32);
      dst[1][ks] = *(const uint4*)(bp1 + k0 + ks * 32);
    }
  };
  auto issueA = [&](float4 (&dst)[4], int k0) {
    dst[0] = *(const float4*)(ap0 + k0);
    dst[1] = *(const float4*)(ap0 + k0 + 4);
    dst[2] = *(const float4*)(ap1 + k0);
    dst[3] = *(const float4*)(ap1 + k0 + 4);
  };
  auto writeA = [&](const float4 (&s)[4]) {
    short8 v0, v1;
    v0[0] = (short)f2bf(s[0].x); v0[1] = (short)f2bf(s[0].y);
    v0[2] = (short)f2bf(s[0].z); v0[3] = (short)f2bf(s[0].w);
    v0[4] = (short)f2bf(s[1].x); v0[5] = (short)f2bf(s[1].y);
    v0[6] = (short)f2bf(s[1].z); v0[7] = (short)f2bf(s[1].w);
    v1[0] = (short)f2bf(s[2].x); v1[1] = (short)f2bf(s[2].y);
    v1[2] = (short)f2bf(s[2].z); v1[3] = (short)f2bf(s[2].w);
    v1[4] = (short)f2bf(s[3].x); v1[5] = (short)f2bf(s[3].y);
    v1[6] = (short)f2bf(s[3].z); v1[7] = (short)f2bf(s[3].w);
    *(short8*)&As[ar][akq * 8]      = v0;   // one ds_write_b128 per row
    *(short8*)&As[ar + 16][akq * 8] = v1;
  };
  auto compute = [&](const uint4 (&bfr)[2][4]) {
    #pragma unroll
    for (int ks = 0; ks < 4; ++ks) {
      short8 a0 = *(const short8*)&As[fm][ks * 32 + kg * 8];
      short8 a1 = *(const short8*)&As[16 + fm][ks * 32 + kg * 8];
      #pragma unroll
      for (int ct = 0; ct < 2; ++ct) {
        short8 b = *(const short8*)&bfr[ct][ks];
        acc[0][ct] = __builtin_amdgcn_mfma_f32_16x16x32_bf16(a0, b, acc[0][ct], 0, 0, 0);
        acc[1][ct] = __builtin_amdgcn_mfma_f32_16x16x32_bf16(a1, b, acc[1][ct], 0, 0, 0);
      }
    }
  };

  // ---- prologue: As <- tile0; bfrA <- tile0; adjB <- tile1 (in flight) ----
  issueA(adjA, 0);
  issueB(bfrA, 0);
  issueA(adjB, BK2);              // NT >= 2 always here
  writeA(adjA);                   // compiler waits vmcnt for adjA only (~12 left in flight)
  asm volatile("s_waitcnt lgkmcnt(0)" ::: "memory");
  __builtin_amdgcn_s_barrier();

  // ---- main loop: 2 logical iters per trip so reg buffers index statically ----
  for (int t = 0; t < NT; t += 2) {
    {   // iter t: compute As(t) x bfrA(t); stage t+1 (adjB->As, bfrB); issue adjA(t+2)
      const int kn1 = (t + 1) * BK2;                       // t+1 <= NT-1
      const int kn2 = ((t + 2) < NT ? (t + 2) : 0) * BK2;
      issueB(bfrB, kn1);
      issueA(adjA, kn2);
      compute(bfrA);
      __builtin_amdgcn_s_barrier();                        // all waves done reading As(t)
      writeA(adjB);                                        // As <- tile t+1
      asm volatile("s_waitcnt lgkmcnt(0)" ::: "memory");
      __builtin_amdgcn_s_barrier();                        // As(t+1) visible
    }
    {   // iter t+1: compute As(t+1) x bfrB; stage t+2 (adjA->As, bfrA); issue adjB(t+3)
      const int u = t + 1;
      const int kn1 = ((u + 1) < NT ? (u + 1) : 0) * BK2;
      const int kn2 = ((u + 2) < NT ? (u + 2) : (u + 2 - NT)) * BK2;
      issueB(bfrA, kn1);
      issueA(adjB, kn2);
      compute(bfrB);
      __builtin_amdgcn_s_barrier();
      writeA(adjA);
      asm volatile("s_waitcnt lgkmcnt(0)" ::: "memory");
      __builtin_amdgcn_s_barrier();
    }
  }

  // ---- epilogue: adaptive-LIF recurrence, exact reference op order ----
  const int T = *tsp;
  #pragma unroll
  for (int rt = 0; rt < 2; ++rt) {
    #pragma unroll
    for (int ct = 0; ct < 2; ++ct) {
      const int col = wave * 32 + ct * 16 + fm;
      const float bv = bias[col];
      #pragma unroll
      for (int i = 0; i < 4; ++i) {
        float I = acc[rt][ct][i] + bv;
        float v = 0.0f, th = 1.0f, sacc = 0.0f;
        for (int t = 0; t < T; ++t) {
          v = v * 0.95f + I;                       // 1 - 1/tau_mem
          float u = v - th;
          float sig = 1.0f / (1.0f + expf(-4.0f * u));
          float hard = (u >= 0.0f) ? 1.0f : 0.0f;
          float s = (hard - sig) + sig;            // straight-through fwd
          sacc += s;
          v = v * (1.0f - s);
          th = th + (1.0f - th) / 60.0f + 0.1f * s;
        }
        const int row = n0 + rt * 16 + kg * 4 + i;
        out[((size_t)batch * N + row) * 128 + col] = sacc / (float)T;
      }
    }
  }
}

extern "C" void kernel_launch(void* const* d_in, const int* in_sizes, int n_in,
                              void* d_out, int out_size, void* d_ws, size_t ws_size,
                              hipStream_t stream) {
  const float* x    = (const float*)d_in[0];
  const float* adj  = (const float*)d_in[1];
  const float* w    = (const float*)d_in[2];
  const float* bias = (const float*)d_in[3];
  const int*   tsp  = (const int*)d_in[4];
  float* out = (float*)d_out;
  unsigned short* supT = (unsigned short*)d_ws;  // 2*128*8192*2B = 4 MB

  const long long sz_x = in_sizes[0];
  const long long sz_adj = in_sizes[1];
  const int N = (int)(sz_adj / sz_x * 128);
  const int B = (int)(sz_x / ((long long)N * 128));
  const int rows = B * N;

  support_kernel<<<rows / 64, 256, 0, stream>>>(x, w, supT, N);
  spike_gemm_kernel<<<dim3(N / 32, B), 256, 0, stream>>>(adj, supT, bias, tsp, out, N);
}